// Round 22
// baseline (197.492 us; speedup 1.0000x reference)
//
#include <hip/hip_runtime.h>

#define D_   256
#define HW_  1024
#define N_   32768
#define K_   1024

#define QMARGS 0.12288f   // flag margin in SCALED (1024*s) units = 1.2e-4 s-units

typedef _Float16 half8 __attribute__((ext_vector_type(8)));     // 8 fp16 (4 VGPRs)
typedef __attribute__((ext_vector_type(4))) float f32x4;        // MFMA acc

#define GLDS(g, l) __builtin_amdgcn_global_load_lds( \
    (const __attribute__((address_space(1))) unsigned int*)(g), \
    (__attribute__((address_space(3))) unsigned int*)(l), 16, 0, 0)

// ws layout (bytes):
//   0      B32[1024]   (4 KB)   -> 4096
//   4096   hbF[1024]   (4 KB)   -> 8192   = 512*B32 (scaled acc-init table)
//   8192   A32[32768]  (128 KB) -> 139264
//   139264 cbAf        (512 KB) -> 663552  (fp16 of -1024*cb in A-frag order)
// zq-region (32 MB) scratch:
//   [0, 16 MB)       zBf   fp16 z b-frags      (= zq batches 0..15)
//   [16 MB, 24 MB)   st4   per-(k8,px) top-4   (8 x 32768 x 32 B)
// finish gathers all batches EXCEPT 16..23 (st4 shadow); gather2 fills them.

// ---------------------------------------------------------------------------
// numpy pairwise fp32 sum of squares over 256 elements (stride in elems).
__device__ __forceinline__ float np_sumsq_256(const float* a, int stride) {
    float blk[2];
    #pragma unroll
    for (int h = 0; h < 2; ++h) {
        const float* p = a + (size_t)h * 128 * stride;
        float r[8];
        #pragma unroll
        for (int j = 0; j < 8; ++j) {
            float v = p[(size_t)j * stride];
            r[j] = __fmul_rn(v, v);
        }
        for (int i = 1; i < 16; ++i) {
            #pragma unroll
            for (int j = 0; j < 8; ++j) {
                float v = p[(size_t)(i * 8 + j) * stride];
                r[j] = __fadd_rn(r[j], __fmul_rn(v, v));
            }
        }
        blk[h] = __fadd_rn(__fadd_rn(__fadd_rn(r[0], r[1]), __fadd_rn(r[2], r[3])),
                           __fadd_rn(__fadd_rn(r[4], r[5]), __fadd_rn(r[6], r[7])));
    }
    return __fadd_rn(blk[0], blk[1]);
}

// ---------------------------------------------------------------------------
// Fused prep (unchanged, validated): bnorm+hbF(0-3) | anorm(4-131) |
// cbsplit(132-259) | zfrag(260-4355)
// ---------------------------------------------------------------------------
__global__ __launch_bounds__(256) void prep_kernel(const float* __restrict__ z,
                                                   const float* __restrict__ cb,
                                                   float* __restrict__ A32,
                                                   float* __restrict__ B32,
                                                   float* __restrict__ hbF,
                                                   half8* __restrict__ cbAf,
                                                   half8* __restrict__ zBf) {
    const int blk = blockIdx.x;
    const int tid = threadIdx.x;
    if (blk < 4) {
        int k = blk * 256 + tid;
        float v = np_sumsq_256(cb + (size_t)k * D_, 1);
        B32[k] = v;
        hbF[k] = 512.0f * v;
    } else if (blk < 132) {
        int n  = (blk - 4) * 256 + tid;
        int b  = n >> 10;
        int hw = n & 1023;
        A32[n] = np_sumsq_256(z + (size_t)b * (D_ * HW_) + hw, HW_);
    } else if (blk < 260) {
        // A-frag order: c = ((kf*8+ds)*64 + q*16 + r) holds -1024*cb[k][d0+j]
        int c  = (blk - 132) * 256 + tid;   // 0..32767
        int kf = c >> 9;
        int ds = (c >> 6) & 7;
        int q  = (c >> 4) & 3;
        int r  = c & 15;
        int k  = kf * 16 + r;
        int d0 = ds * 32 + q * 8;
        const float* src = cb + (size_t)k * D_ + d0;
        half8 v;
        #pragma unroll
        for (int j = 0; j < 8; ++j) v[j] = (_Float16)(src[j] * -1024.0f);
        cbAf[c] = v;
    } else {
        // B-frag order: c = (pxg*8+ds)*64 + lane holds z[px][d0+j] as fp16
        int c    = (blk - 260) * 256 + tid;  // 0..1048575
        int pxg  = c >> 9;
        int ds   = (c >> 6) & 7;
        int lane = c & 63;
        int q    = lane >> 4;
        int r    = lane & 15;
        int px   = pxg * 16 + r;
        int bb   = px >> 10;
        int hw   = px & 1023;
        int d0   = ds * 32 + q * 8;
        const float* src = z + (size_t)bb * (D_ * HW_) + hw;
        half8 v;
        #pragma unroll
        for (int j = 0; j < 8; ++j) v[j] = (_Float16)src[(size_t)(d0 + j) * HW_];
        zBf[c] = v;
    }
}

// lex compare-swap: keep smaller (v,k) in (va,ka)
#define CSWAP(va, ka, vb, kb) { \
    bool sw = (vb < va) || (vb == va && kb < ka); \
    float tv = va; int tk = ka; \
    va = sw ? vb : va; ka = sw ? kb : ka; \
    vb = sw ? tv : vb; kb = sw ? tk : kb; }

// sorted top-4 insert (ascending; ascending-k scan => first-occurrence ties)
#define TOP4_INS(S, KK, V0,K0,V1,K1,V2,K2,V3,K3) \
    if (S < V3) { \
        if (S < V1) { \
            V3 = V2; K3 = K2; V2 = V1; K2 = K1; \
            if (S < V0) { V1 = V0; K1 = K0; V0 = S; K0 = KK; } \
            else        { V1 = S;  K1 = KK; } \
        } else { \
            if (S < V2) { V3 = V2; K3 = K2; V2 = S; K2 = KK; } \
            else        { V3 = S;  K3 = KK; } \
        } \
    }

// merge the 4 q-lanes' sorted-4 lists (xor 16 then 32): bitonic
#define QMERGE(V0,K0,V1,K1,V2,K2,V3,K3) \
    _Pragma("unroll") \
    for (int off = 16; off <= 32; off <<= 1) { \
        float b0 = __shfl_xor(V0, off, 64), b1 = __shfl_xor(V1, off, 64); \
        float b2 = __shfl_xor(V2, off, 64), b3 = __shfl_xor(V3, off, 64); \
        int   c0 = __shfl_xor(K0, off, 64), c1 = __shfl_xor(K1, off, 64); \
        int   c2 = __shfl_xor(K2, off, 64), c3 = __shfl_xor(K3, off, 64); \
        CSWAP(V0, K0, b3, c3); CSWAP(V1, K1, b2, c2); \
        CSWAP(V2, K2, b1, c1); CSWAP(V3, K3, b0, c0); \
        CSWAP(V0, K0, V2, K2); CSWAP(V1, K1, V3, K3); \
        CSWAP(V0, K0, V1, K1); CSWAP(V2, K2, V3, K3); \
    }

// merge two sorted-4 lists (b consumed) -> sorted-4 in a
#define MERGE2(V0,K0,V1,K1,V2,K2,V3,K3, W0,P0,W1,P1,W2,P2,W3,P3) { \
    CSWAP(V0, K0, W3, P3); CSWAP(V1, K1, W2, P2); \
    CSWAP(V2, K2, W1, P1); CSWAP(V3, K3, W0, P0); \
    CSWAP(V0, K0, V2, K2); CSWAP(V1, K1, V3, K3); \
    CSWAP(V0, K0, V1, K1); CSWAP(V2, K2, V3, K3); }

// ---------------------------------------------------------------------------
// Screening v13: K-EIGHTHS. Block = 4 waves x 128 px x 128 codes (one k8),
// chunk = 16 codes (8 KB slab). LDS 16 KB -> 8 blocks/CU; grid 2048 ->
// 32 waves/CU (8/SIMD), 2x R20's latency hiding. One hbF float4 inits both
// pixel-set accs (codes shared). Per-wave sorted top-4 -> st4[k8][px].
// ---------------------------------------------------------------------------
__global__ __launch_bounds__(256, 8) void vq_screen13(
        const half8* __restrict__ zBf,
        const half8* __restrict__ cbAf,
        const float* __restrict__ hbF,
        float* __restrict__ st4)
{
    __shared__ half8 abuf[2][512];    // [dbuf][8KB chunk slab] = 16 KB

    const int tid  = threadIdx.x;
    const int lane = tid & 63;
    const int wave = tid >> 6;        // 0..3
    const int q    = lane >> 4;
    const int r    = lane & 15;

    const int tile = blockIdx.x >> 3;     // 0..255 (128-px tile)
    const int k8   = blockIdx.x & 7;      // K-eighth (128 codes)

    // two register b-frag sets (16 px each) -> 32 px per wave
    const int f0 = tile * 8 + wave * 2;
    half8 b0[8], b1[8];
    #pragma unroll
    for (int ds = 0; ds < 8; ++ds) {
        b0[ds] = zBf[(size_t)(f0 * 8 + ds) * 64 + lane];
        b1[ds] = zBf[(size_t)((f0 + 1) * 8 + ds) * 64 + lane];
    }

    // staging: each wave stages 2KB (2 x 1KB GLDS) of the 8KB chunk slab
    const char* gbase = (const char*)cbAf + (size_t)k8 * 65536
                      + wave * 2048 + lane * 16;
    const int   ldsOff = wave * 128;   // half8 units (2 KB)

    {   // prologue: stage chunk 0 into buf 0
        char* d = (char*)&abuf[0][ldsOff];
        GLDS(gbase, d);
        GLDS(gbase + 1024, d + 1024);
    }
    __syncthreads();

    float v0a = 3.4e38f, v1a = 3.4e38f, v2a = 3.4e38f, v3a = 3.4e38f;
    int   k0a = 0x7fffffff, k1a = 0x7fffffff, k2a = 0x7fffffff, k3a = 0x7fffffff;
    float v0b = 3.4e38f, v1b = 3.4e38f, v2b = 3.4e38f, v3b = 3.4e38f;
    int   k0b = 0x7fffffff, k1b = 0x7fffffff, k2b = 0x7fffffff, k3b = 0x7fffffff;

    for (int chl = 0; chl < 8; ++chl) {
        const int cur = chl & 1;
        if (chl < 7) {
            const char* s = gbase + (size_t)(chl + 1) * 8192;
            char* d = (char*)&abuf[cur ^ 1][ldsOff];
            GLDS(s, d);
            GLDS(s + 1024, d + 1024);
        }

        const int kbase = k8 * 128 + chl * 16;
        const float4 h = *reinterpret_cast<const float4*>(&hbF[kbase + q * 4]);
        f32x4 a00 = {h.x, h.y, h.z, h.w};     // set a (pixels f0)
        f32x4 a01 = a00;                      // set b (pixels f0+1)

        #pragma unroll
        for (int ds = 0; ds < 8; ++ds) {
            half8 A0 = abuf[cur][ds * 64 + lane];
            a00 = __builtin_amdgcn_mfma_f32_16x16x32_f16(A0, b0[ds], a00, 0,0,0);
            a01 = __builtin_amdgcn_mfma_f32_16x16x32_f16(A0, b1[ds], a01, 0,0,0);
        }

        // acc IS 1024*s. min4 gate -> sorted top-4 (ascending k order kept)
        float ma = fminf(fminf(a00[0], a00[1]), fminf(a00[2], a00[3]));
        float mb = fminf(fminf(a01[0], a01[1]), fminf(a01[2], a01[3]));
        if (ma < v3a) {
            #pragma unroll
            for (int i = 0; i < 4; ++i) {
                int kk  = kbase + q * 4 + i;
                float s = a00[i];
                TOP4_INS(s, kk, v0a,k0a, v1a,k1a, v2a,k2a, v3a,k3a);
            }
        }
        if (mb < v3b) {
            #pragma unroll
            for (int i = 0; i < 4; ++i) {
                int kk  = kbase + q * 4 + i;
                float s = a01[i];
                TOP4_INS(s, kk, v0b,k0b, v1b,k1b, v2b,k2b, v3b,k3b);
            }
        }
        __syncthreads();
    }

    // merge the 4 q-lanes per pixel (per set); q==0 lanes write st4
    QMERGE(v0a,k0a, v1a,k1a, v2a,k2a, v3a,k3a);
    QMERGE(v0b,k0b, v1b,k1b, v2b,k2b, v3b,k3b);

    if (q == 0) {
        {   // set a: px = tile*128 + wave*32 + r
            int n = tile * 128 + wave * 32 + r;
            float* p = st4 + ((size_t)k8 * N_ + n) * 8;
            *reinterpret_cast<float4*>(p)     = make_float4(v0a, v1a, v2a, v3a);
            *reinterpret_cast<float4*>(p + 4) = make_float4(
                __int_as_float(k0a), __int_as_float(k1a),
                __int_as_float(k2a), __int_as_float(k3a));
        }
        {   // set b: px = tile*128 + wave*32 + 16 + r
            int n = tile * 128 + wave * 32 + 16 + r;
            float* p = st4 + ((size_t)k8 * N_ + n) * 8;
            *reinterpret_cast<float4*>(p)     = make_float4(v0b, v1b, v2b, v3b);
            *reinterpret_cast<float4*>(p + 4) = make_float4(
                __int_as_float(k0b), __int_as_float(k1b),
                __int_as_float(k2b), __int_as_float(k3b));
        }
    }
}

// ---------------------------------------------------------------------------
// Fused finish: per-pixel 8-way merge of k8 top-4s + flag + in-block exact
// fp64->d32 resolution + gather. Blocks covering zq batches 16..23 (st4
// shadow) skip ONLY the zq store; gather2 fills those afterwards.
// ---------------------------------------------------------------------------
__global__ __launch_bounds__(256) void finish_kernel(
        const float* __restrict__ st4,
        const float* __restrict__ A32,
        const float* __restrict__ B32,
        const float* __restrict__ cb,
        const float* __restrict__ z,
        float* __restrict__ oidx,
        float* __restrict__ zq)
{
    __shared__ int fcount;
    __shared__ int flist[64];
    __shared__ int fck[64][4];
    __shared__ int fidx[64];

    const int tid  = threadIdx.x;
    const int lane = tid & 63;
    const int wave = tid >> 6;
    const int p0   = blockIdx.x * 64;

    if (tid == 0) fcount = 0;
    __syncthreads();

    // ---- phase 1: merge + flag (one thread per pixel) ----
    if (tid < 64) {
        const int n = p0 + tid;
        float V0, V1, V2, V3; int K0, K1, K2, K3;
        {
            const float* p = st4 + (size_t)n * 8;            // k8 = 0
            float4 v  = *reinterpret_cast<const float4*>(p);
            float4 kf = *reinterpret_cast<const float4*>(p + 4);
            V0 = v.x; V1 = v.y; V2 = v.z; V3 = v.w;
            K0 = __float_as_int(kf.x); K1 = __float_as_int(kf.y);
            K2 = __float_as_int(kf.z); K3 = __float_as_int(kf.w);
        }
        #pragma unroll
        for (int k8 = 1; k8 < 8; ++k8) {
            const float* p = st4 + ((size_t)k8 * N_ + n) * 8;
            float4 v  = *reinterpret_cast<const float4*>(p);
            float4 kf = *reinterpret_cast<const float4*>(p + 4);
            float W0 = v.x, W1 = v.y, W2 = v.z, W3 = v.w;
            int   P0 = __float_as_int(kf.x), P1 = __float_as_int(kf.y);
            int   P2 = __float_as_int(kf.z), P3 = __float_as_int(kf.w);
            MERGE2(V0,K0, V1,K1, V2,K2, V3,K3, W0,P0, W1,P1, W2,P2, W3,P3);
        }
        fidx[tid] = K0;
        oidx[n] = (float)K0;
        if (V1 - V0 < QMARGS) {
            int slot = atomicAdd(&fcount, 1);
            flist[slot] = tid;
            fck[slot][0] = K0; fck[slot][1] = K1;
            fck[slot][2] = K2; fck[slot][3] = K3;
        }
    }
    __syncthreads();

    // ---- phase 2: exact resolution of flagged pixels (one wave each) ----
    const int fc = fcount;
    for (int i = wave; i < fc; i += 4) {
        const int pl = flist[i];
        const int nn = p0 + pl;
        const int bb = nn >> 10, hw = nn & 1023;
        const float* zb = z + (size_t)bb * (D_ * HW_) + hw;
        float zf[4];
        #pragma unroll
        for (int j = 0; j < 4; ++j) zf[j] = zb[(size_t)(lane * 4 + j) * HW_];

        const float An = A32[nn];
        float bd = 3.4e38f;
        int   bk = 0x7fffffff;
        #pragma unroll
        for (int c = 0; c < 4; ++c) {
            int k = fck[i][c];
            float4 c4 = *reinterpret_cast<const float4*>(cb + (size_t)k * D_ + lane * 4);
            double acc = 0.0;
            acc = fma((double)c4.x, (double)zf[0], acc);
            acc = fma((double)c4.y, (double)zf[1], acc);
            acc = fma((double)c4.z, (double)zf[2], acc);
            acc = fma((double)c4.w, (double)zf[3], acc);
            #pragma unroll
            for (int off = 1; off <= 32; off <<= 1) acc += __shfl_xor(acc, off, 64);
            float C32 = (float)acc;
            float d32 = __fsub_rn(__fadd_rn(An, B32[k]), __fadd_rn(C32, C32));
            if (d32 < bd || (d32 == bd && k < bk)) { bd = d32; bk = k; }
        }
        if (lane == 0) { oidx[nn] = (float)bk; fidx[pl] = bk; }
    }
    __syncthreads();

    // ---- phase 3: gather (skip st4-shadowed batches 16..23) ----
    if (p0 >= 16384 && p0 < 24576) return;
    const int s_nl = tid & 63;
    const int s_dw = tid >> 6;
    const int b    = p0 >> 10;
    const int hw0  = p0 & 1023;
    const int idxn = fidx[s_nl];
    const float4* crow = reinterpret_cast<const float4*>(cb + (size_t)idxn * D_);
    float* zqb = zq + (size_t)b * (D_ * HW_) + hw0;
    #pragma unroll
    for (int rr = 0; rr < 16; ++rr) {
        int d4 = s_dw * 16 + rr;
        float4 c4 = crow[d4];
        int d = d4 * 4;
        zqb[(size_t)(d + 0) * HW_ + s_nl] = c4.x;
        zqb[(size_t)(d + 1) * HW_ + s_nl] = c4.y;
        zqb[(size_t)(d + 2) * HW_ + s_nl] = c4.z;
        zqb[(size_t)(d + 3) * HW_ + s_nl] = c4.w;
    }
}

// ---------------------------------------------------------------------------
// gather2: fills zq batches 16..23 after finish completes (st4 dead).
// ---------------------------------------------------------------------------
__global__ __launch_bounds__(256) void gather2_kernel(const float* __restrict__ cb,
                                                      const float* __restrict__ oidx,
                                                      float* __restrict__ zq,
                                                      int base) {
    const int tid  = threadIdx.x;
    const int s_nl = tid & 63;
    const int s_dw = tid >> 6;
    const int p0   = base + blockIdx.x * 64;
    const int b    = p0 >> 10;
    const int hw0  = p0 & 1023;

    int idxn = (int)oidx[p0 + s_nl];
    const float4* crow = reinterpret_cast<const float4*>(cb + (size_t)idxn * D_);
    float* zqb = zq + (size_t)b * (D_ * HW_) + hw0;
    #pragma unroll
    for (int r = 0; r < 16; ++r) {
        int d4 = s_dw * 16 + r;
        float4 c4 = crow[d4];
        int d = d4 * 4;
        zqb[(size_t)(d + 0) * HW_ + s_nl] = c4.x;
        zqb[(size_t)(d + 1) * HW_ + s_nl] = c4.y;
        zqb[(size_t)(d + 2) * HW_ + s_nl] = c4.z;
        zqb[(size_t)(d + 3) * HW_ + s_nl] = c4.w;
    }
}

extern "C" void kernel_launch(void* const* d_in, const int* in_sizes, int n_in,
                              void* d_out, int out_size, void* d_ws, size_t ws_size,
                              hipStream_t stream) {
    const float* z  = (const float*)d_in[0];   // [32,256,32,32] fp32
    const float* cb = (const float*)d_in[1];   // [1024,256] fp32

    float* zq   = (float*)d_out;
    float* oidx = zq + (size_t)N_ * D_;        // byte 33554432

    char* ws = (char*)d_ws;
    float* B32  = (float*)(ws + 0);
    float* hbF  = (float*)(ws + 4096);
    float* A32  = (float*)(ws + 8192);
    half8* cbAf = (half8*)(ws + 139264);       // ends 663552

    // zq-region scratch: zBf [0,16MB), st4 [16MB,24MB)
    char*  zqb = (char*)zq;
    half8* zBf = (half8*)zqb;                  // 16 MB
    float* st4 = (float*)(zqb + 16777216);     // 8 MB (= batches 16..23)

    prep_kernel<<<4356, 256, 0, stream>>>(z, cb, A32, B32, hbF, cbAf, zBf);
    vq_screen13<<<2048, 256, 0, stream>>>(zBf, cbAf, hbF, st4);
    finish_kernel<<<N_ / 64, 256, 0, stream>>>(st4, A32, B32, cb, z, oidx, zq);
    gather2_kernel<<<128, 256, 0, stream>>>(cb, oidx, zq, 16384);
}

// Round 23
// 119.878 us; speedup vs baseline: 1.6475x; 1.6475x over previous
//
#include <hip/hip_runtime.h>

#define D_   256
#define HW_  1024
#define N_   32768
#define K_   1024

#define QMARGS 0.12288f   // flag margin in SCALED (1024*s) units = 1.2e-4 s-units

typedef _Float16 half8 __attribute__((ext_vector_type(8)));     // 8 fp16 (4 VGPRs)
typedef __attribute__((ext_vector_type(4))) float f32x4;        // MFMA acc

#define GLDS(g, l) __builtin_amdgcn_global_load_lds( \
    (const __attribute__((address_space(1))) unsigned int*)(g), \
    (__attribute__((address_space(3))) unsigned int*)(l), 16, 0, 0)

// ws layout (bytes):
//   0      B32[1024]   (4 KB)   -> 4096
//   4096   hbF[1024]   (4 KB)   -> 8192   = 512*B32 (scaled acc-init table)
//   8192   A32[32768]  (128 KB) -> 139264
//   139264 cbAf        (512 KB) -> 663552  (fp16 of -1024*cb in A-frag order)
// zq-region (32 MB) scratch:
//   [0, 16 MB)       zBf   fp16 z b-frags      (= zq batches 0..15)
//   [16 MB, 24 MB)   st4   per-(k8,px) top-4   (8 x 32768 x 32 B)
// finish gathers all batches EXCEPT 16..23 (st4 shadow); gather2 fills them.

// ---------------------------------------------------------------------------
// numpy pairwise fp32 sum of squares over 256 elements (stride in elems).
__device__ __forceinline__ float np_sumsq_256(const float* a, int stride) {
    float blk[2];
    #pragma unroll
    for (int h = 0; h < 2; ++h) {
        const float* p = a + (size_t)h * 128 * stride;
        float r[8];
        #pragma unroll
        for (int j = 0; j < 8; ++j) {
            float v = p[(size_t)j * stride];
            r[j] = __fmul_rn(v, v);
        }
        for (int i = 1; i < 16; ++i) {
            #pragma unroll
            for (int j = 0; j < 8; ++j) {
                float v = p[(size_t)(i * 8 + j) * stride];
                r[j] = __fadd_rn(r[j], __fmul_rn(v, v));
            }
        }
        blk[h] = __fadd_rn(__fadd_rn(__fadd_rn(r[0], r[1]), __fadd_rn(r[2], r[3])),
                           __fadd_rn(__fadd_rn(r[4], r[5]), __fadd_rn(r[6], r[7])));
    }
    return __fadd_rn(blk[0], blk[1]);
}

// ---------------------------------------------------------------------------
// Fused prep (unchanged, validated): bnorm+hbF(0-3) | anorm(4-131) |
// cbsplit(132-259) | zfrag(260-4355)
// ---------------------------------------------------------------------------
__global__ __launch_bounds__(256) void prep_kernel(const float* __restrict__ z,
                                                   const float* __restrict__ cb,
                                                   float* __restrict__ A32,
                                                   float* __restrict__ B32,
                                                   float* __restrict__ hbF,
                                                   half8* __restrict__ cbAf,
                                                   half8* __restrict__ zBf) {
    const int blk = blockIdx.x;
    const int tid = threadIdx.x;
    if (blk < 4) {
        int k = blk * 256 + tid;
        float v = np_sumsq_256(cb + (size_t)k * D_, 1);
        B32[k] = v;
        hbF[k] = 512.0f * v;
    } else if (blk < 132) {
        int n  = (blk - 4) * 256 + tid;
        int b  = n >> 10;
        int hw = n & 1023;
        A32[n] = np_sumsq_256(z + (size_t)b * (D_ * HW_) + hw, HW_);
    } else if (blk < 260) {
        // A-frag order: c = ((kf*8+ds)*64 + q*16 + r) holds -1024*cb[k][d0+j]
        int c  = (blk - 132) * 256 + tid;   // 0..32767
        int kf = c >> 9;
        int ds = (c >> 6) & 7;
        int q  = (c >> 4) & 3;
        int r  = c & 15;
        int k  = kf * 16 + r;
        int d0 = ds * 32 + q * 8;
        const float* src = cb + (size_t)k * D_ + d0;
        half8 v;
        #pragma unroll
        for (int j = 0; j < 8; ++j) v[j] = (_Float16)(src[j] * -1024.0f);
        cbAf[c] = v;
    } else {
        // B-frag order: c = (pxg*8+ds)*64 + lane holds z[px][d0+j] as fp16
        int c    = (blk - 260) * 256 + tid;  // 0..1048575
        int pxg  = c >> 9;
        int ds   = (c >> 6) & 7;
        int lane = c & 63;
        int q    = lane >> 4;
        int r    = lane & 15;
        int px   = pxg * 16 + r;
        int bb   = px >> 10;
        int hw   = px & 1023;
        int d0   = ds * 32 + q * 8;
        const float* src = z + (size_t)bb * (D_ * HW_) + hw;
        half8 v;
        #pragma unroll
        for (int j = 0; j < 8; ++j) v[j] = (_Float16)src[(size_t)(d0 + j) * HW_];
        zBf[c] = v;
    }
}

// lex compare-swap: keep smaller (v,k) in (va,ka)
#define CSWAP(va, ka, vb, kb) { \
    bool sw = (vb < va) || (vb == va && kb < ka); \
    float tv = va; int tk = ka; \
    va = sw ? vb : va; ka = sw ? kb : ka; \
    vb = sw ? tv : vb; kb = sw ? tk : kb; }

// sorted top-4 insert (ascending; ascending-k scan => first-occurrence ties)
#define TOP4_INS(S, KK, V0,K0,V1,K1,V2,K2,V3,K3) \
    if (S < V3) { \
        if (S < V1) { \
            V3 = V2; K3 = K2; V2 = V1; K2 = K1; \
            if (S < V0) { V1 = V0; K1 = K0; V0 = S; K0 = KK; } \
            else        { V1 = S;  K1 = KK; } \
        } else { \
            if (S < V2) { V3 = V2; K3 = K2; V2 = S; K2 = KK; } \
            else        { V3 = S;  K3 = KK; } \
        } \
    }

// merge the 4 q-lanes' sorted-4 lists (xor 16 then 32): bitonic
#define QMERGE(V0,K0,V1,K1,V2,K2,V3,K3) \
    _Pragma("unroll") \
    for (int off = 16; off <= 32; off <<= 1) { \
        float b0_ = __shfl_xor(V0, off, 64), b1_ = __shfl_xor(V1, off, 64); \
        float b2_ = __shfl_xor(V2, off, 64), b3_ = __shfl_xor(V3, off, 64); \
        int   c0_ = __shfl_xor(K0, off, 64), c1_ = __shfl_xor(K1, off, 64); \
        int   c2_ = __shfl_xor(K2, off, 64), c3_ = __shfl_xor(K3, off, 64); \
        CSWAP(V0, K0, b3_, c3_); CSWAP(V1, K1, b2_, c2_); \
        CSWAP(V2, K2, b1_, c1_); CSWAP(V3, K3, b0_, c0_); \
        CSWAP(V0, K0, V2, K2); CSWAP(V1, K1, V3, K3); \
        CSWAP(V0, K0, V1, K1); CSWAP(V2, K2, V3, K3); \
    }

// merge two sorted-4 lists (b consumed) -> sorted-4 in a
#define MERGE2(V0,K0,V1,K1,V2,K2,V3,K3, W0,P0,W1,P1,W2,P2,W3,P3) { \
    CSWAP(V0, K0, W3, P3); CSWAP(V1, K1, W2, P2); \
    CSWAP(V2, K2, W1, P1); CSWAP(V3, K3, W0, P0); \
    CSWAP(V0, K0, V2, K2); CSWAP(V1, K1, V3, K3); \
    CSWAP(V0, K0, V1, K1); CSWAP(V2, K2, V3, K3); }

// ---------------------------------------------------------------------------
// Screening v14: K-eighths at 64-VGPR budget. ONE b-frag set per wave (16 px)
// -> ~58 VGPR fits __launch_bounds__(256,8) without spill (R22 spilled:
// 2 sets = 64 VGPR of frags alone -> scratch, FETCH 400 MB). Block = 4 waves
// x 64 px x 128 codes; LDS 16 KB; grid 4096 -> 8 blocks/CU, 32 waves/CU.
// ---------------------------------------------------------------------------
__global__ __launch_bounds__(256, 8) void vq_screen14(
        const half8* __restrict__ zBf,
        const half8* __restrict__ cbAf,
        const float* __restrict__ hbF,
        float* __restrict__ st4)
{
    __shared__ half8 abuf[2][512];    // [dbuf][8KB chunk slab] = 16 KB

    const int tid  = threadIdx.x;
    const int lane = tid & 63;
    const int wave = tid >> 6;        // 0..3
    const int q    = lane >> 4;
    const int r    = lane & 15;

    const int tile = blockIdx.x >> 3;     // 0..511 (64-px tile)
    const int k8   = blockIdx.x & 7;      // K-eighth (128 codes)

    // one register b-frag set (16 px per wave)
    const int f0 = tile * 4 + wave;
    half8 b0[8];
    #pragma unroll
    for (int ds = 0; ds < 8; ++ds)
        b0[ds] = zBf[(size_t)(f0 * 8 + ds) * 64 + lane];

    // staging: each wave stages 2KB (2 x 1KB GLDS) of the 8KB chunk slab
    const char* gbase = (const char*)cbAf + (size_t)k8 * 65536
                      + wave * 2048 + lane * 16;
    const int   ldsOff = wave * 128;   // half8 units (2 KB)

    {   // prologue: stage chunk 0 into buf 0
        char* d = (char*)&abuf[0][ldsOff];
        GLDS(gbase, d);
        GLDS(gbase + 1024, d + 1024);
    }
    __syncthreads();

    float v0 = 3.4e38f, v1 = 3.4e38f, v2 = 3.4e38f, v3 = 3.4e38f;
    int   k0 = 0x7fffffff, k1 = 0x7fffffff, k2 = 0x7fffffff, k3 = 0x7fffffff;

    for (int chl = 0; chl < 8; ++chl) {
        const int cur = chl & 1;
        if (chl < 7) {
            const char* s = gbase + (size_t)(chl + 1) * 8192;
            char* d = (char*)&abuf[cur ^ 1][ldsOff];
            GLDS(s, d);
            GLDS(s + 1024, d + 1024);
        }

        const int kbase = k8 * 128 + chl * 16;
        const float4 h = *reinterpret_cast<const float4*>(&hbF[kbase + q * 4]);
        f32x4 acc = {h.x, h.y, h.z, h.w};

        #pragma unroll
        for (int ds = 0; ds < 8; ++ds) {
            half8 A0 = abuf[cur][ds * 64 + lane];
            acc = __builtin_amdgcn_mfma_f32_16x16x32_f16(A0, b0[ds], acc, 0,0,0);
        }

        // acc IS 1024*s. min4 gate -> sorted top-4 (ascending k order kept)
        float mg = fminf(fminf(acc[0], acc[1]), fminf(acc[2], acc[3]));
        if (mg < v3) {
            #pragma unroll
            for (int i = 0; i < 4; ++i) {
                int kk  = kbase + q * 4 + i;
                float s = acc[i];
                TOP4_INS(s, kk, v0,k0, v1,k1, v2,k2, v3,k3);
            }
        }
        __syncthreads();
    }

    // merge the 4 q-lanes per pixel; q==0 lanes write st4
    QMERGE(v0,k0, v1,k1, v2,k2, v3,k3);

    if (q == 0) {
        int n = tile * 64 + wave * 16 + r;
        float* p = st4 + ((size_t)k8 * N_ + n) * 8;
        *reinterpret_cast<float4*>(p)     = make_float4(v0, v1, v2, v3);
        *reinterpret_cast<float4*>(p + 4) = make_float4(
            __int_as_float(k0), __int_as_float(k1),
            __int_as_float(k2), __int_as_float(k3));
    }
}

// ---------------------------------------------------------------------------
// Fused finish (unchanged from R22): 8-way merge + flag + in-block exact
// fp64->d32 resolution + gather (skips st4-shadowed batches 16..23).
// ---------------------------------------------------------------------------
__global__ __launch_bounds__(256) void finish_kernel(
        const float* __restrict__ st4,
        const float* __restrict__ A32,
        const float* __restrict__ B32,
        const float* __restrict__ cb,
        const float* __restrict__ z,
        float* __restrict__ oidx,
        float* __restrict__ zq)
{
    __shared__ int fcount;
    __shared__ int flist[64];
    __shared__ int fck[64][4];
    __shared__ int fidx[64];

    const int tid  = threadIdx.x;
    const int lane = tid & 63;
    const int wave = tid >> 6;
    const int p0   = blockIdx.x * 64;

    if (tid == 0) fcount = 0;
    __syncthreads();

    if (tid < 64) {
        const int n = p0 + tid;
        float V0, V1, V2, V3; int K0, K1, K2, K3;
        {
            const float* p = st4 + (size_t)n * 8;            // k8 = 0
            float4 v  = *reinterpret_cast<const float4*>(p);
            float4 kf = *reinterpret_cast<const float4*>(p + 4);
            V0 = v.x; V1 = v.y; V2 = v.z; V3 = v.w;
            K0 = __float_as_int(kf.x); K1 = __float_as_int(kf.y);
            K2 = __float_as_int(kf.z); K3 = __float_as_int(kf.w);
        }
        #pragma unroll
        for (int k8 = 1; k8 < 8; ++k8) {
            const float* p = st4 + ((size_t)k8 * N_ + n) * 8;
            float4 v  = *reinterpret_cast<const float4*>(p);
            float4 kf = *reinterpret_cast<const float4*>(p + 4);
            float W0 = v.x, W1 = v.y, W2 = v.z, W3 = v.w;
            int   P0 = __float_as_int(kf.x), P1 = __float_as_int(kf.y);
            int   P2 = __float_as_int(kf.z), P3 = __float_as_int(kf.w);
            MERGE2(V0,K0, V1,K1, V2,K2, V3,K3, W0,P0, W1,P1, W2,P2, W3,P3);
        }
        fidx[tid] = K0;
        oidx[n] = (float)K0;
        if (V1 - V0 < QMARGS) {
            int slot = atomicAdd(&fcount, 1);
            flist[slot] = tid;
            fck[slot][0] = K0; fck[slot][1] = K1;
            fck[slot][2] = K2; fck[slot][3] = K3;
        }
    }
    __syncthreads();

    const int fc = fcount;
    for (int i = wave; i < fc; i += 4) {
        const int pl = flist[i];
        const int nn = p0 + pl;
        const int bb = nn >> 10, hw = nn & 1023;
        const float* zb = z + (size_t)bb * (D_ * HW_) + hw;
        float zf[4];
        #pragma unroll
        for (int j = 0; j < 4; ++j) zf[j] = zb[(size_t)(lane * 4 + j) * HW_];

        const float An = A32[nn];
        float bd = 3.4e38f;
        int   bk = 0x7fffffff;
        #pragma unroll
        for (int c = 0; c < 4; ++c) {
            int k = fck[i][c];
            float4 c4 = *reinterpret_cast<const float4*>(cb + (size_t)k * D_ + lane * 4);
            double acc = 0.0;
            acc = fma((double)c4.x, (double)zf[0], acc);
            acc = fma((double)c4.y, (double)zf[1], acc);
            acc = fma((double)c4.z, (double)zf[2], acc);
            acc = fma((double)c4.w, (double)zf[3], acc);
            #pragma unroll
            for (int off = 1; off <= 32; off <<= 1) acc += __shfl_xor(acc, off, 64);
            float C32 = (float)acc;
            float d32 = __fsub_rn(__fadd_rn(An, B32[k]), __fadd_rn(C32, C32));
            if (d32 < bd || (d32 == bd && k < bk)) { bd = d32; bk = k; }
        }
        if (lane == 0) { oidx[nn] = (float)bk; fidx[pl] = bk; }
    }
    __syncthreads();

    if (p0 >= 16384 && p0 < 24576) return;
    const int s_nl = tid & 63;
    const int s_dw = tid >> 6;
    const int b    = p0 >> 10;
    const int hw0  = p0 & 1023;
    const int idxn = fidx[s_nl];
    const float4* crow = reinterpret_cast<const float4*>(cb + (size_t)idxn * D_);
    float* zqb = zq + (size_t)b * (D_ * HW_) + hw0;
    #pragma unroll
    for (int rr = 0; rr < 16; ++rr) {
        int d4 = s_dw * 16 + rr;
        float4 c4 = crow[d4];
        int d = d4 * 4;
        zqb[(size_t)(d + 0) * HW_ + s_nl] = c4.x;
        zqb[(size_t)(d + 1) * HW_ + s_nl] = c4.y;
        zqb[(size_t)(d + 2) * HW_ + s_nl] = c4.z;
        zqb[(size_t)(d + 3) * HW_ + s_nl] = c4.w;
    }
}

// ---------------------------------------------------------------------------
__global__ __launch_bounds__(256) void gather2_kernel(const float* __restrict__ cb,
                                                      const float* __restrict__ oidx,
                                                      float* __restrict__ zq,
                                                      int base) {
    const int tid  = threadIdx.x;
    const int s_nl = tid & 63;
    const int s_dw = tid >> 6;
    const int p0   = base + blockIdx.x * 64;
    const int b    = p0 >> 10;
    const int hw0  = p0 & 1023;

    int idxn = (int)oidx[p0 + s_nl];
    const float4* crow = reinterpret_cast<const float4*>(cb + (size_t)idxn * D_);
    float* zqb = zq + (size_t)b * (D_ * HW_) + hw0;
    #pragma unroll
    for (int r = 0; r < 16; ++r) {
        int d4 = s_dw * 16 + r;
        float4 c4 = crow[d4];
        int d = d4 * 4;
        zqb[(size_t)(d + 0) * HW_ + s_nl] = c4.x;
        zqb[(size_t)(d + 1) * HW_ + s_nl] = c4.y;
        zqb[(size_t)(d + 2) * HW_ + s_nl] = c4.z;
        zqb[(size_t)(d + 3) * HW_ + s_nl] = c4.w;
    }
}

extern "C" void kernel_launch(void* const* d_in, const int* in_sizes, int n_in,
                              void* d_out, int out_size, void* d_ws, size_t ws_size,
                              hipStream_t stream) {
    const float* z  = (const float*)d_in[0];   // [32,256,32,32] fp32
    const float* cb = (const float*)d_in[1];   // [1024,256] fp32

    float* zq   = (float*)d_out;
    float* oidx = zq + (size_t)N_ * D_;        // byte 33554432

    char* ws = (char*)d_ws;
    float* B32  = (float*)(ws + 0);
    float* hbF  = (float*)(ws + 4096);
    float* A32  = (float*)(ws + 8192);
    half8* cbAf = (half8*)(ws + 139264);       // ends 663552

    // zq-region scratch: zBf [0,16MB), st4 [16MB,24MB)
    char*  zqb = (char*)zq;
    half8* zBf = (half8*)zqb;                  // 16 MB
    float* st4 = (float*)(zqb + 16777216);     // 8 MB (= batches 16..23)

    prep_kernel<<<4356, 256, 0, stream>>>(z, cb, A32, B32, hbF, cbAf, zBf);
    vq_screen14<<<4096, 256, 0, stream>>>(zBf, cbAf, hbF, st4);
    finish_kernel<<<N_ / 64, 256, 0, stream>>>(st4, A32, B32, cb, z, oidx, zq);
    gather2_kernel<<<128, 256, 0, stream>>>(cb, oidx, zq, 16384);
}

// Round 24
// 98.840 us; speedup vs baseline: 1.9981x; 1.2128x over previous
//
#include <hip/hip_runtime.h>

#define D_   256
#define HW_  1024
#define N_   32768
#define K_   1024

#define QMARGS 0.12288f   // flag margin in SCALED (1024*s) units = 1.2e-4 s-units

typedef _Float16 half8 __attribute__((ext_vector_type(8)));     // 8 fp16 (4 VGPRs)
typedef __attribute__((ext_vector_type(4))) float f32x4;        // MFMA acc

#define GLDS(g, l) __builtin_amdgcn_global_load_lds( \
    (const __attribute__((address_space(1))) unsigned int*)(g), \
    (__attribute__((address_space(3))) unsigned int*)(l), 16, 0, 0)

// ws layout (bytes):
//   0      B32[1024]   (4 KB)   -> 4096
//   4096   hbF[1024]   (4 KB)   -> 8192   = 512*B32 (scaled acc-init table)
//   8192   A32[32768]  (128 KB) -> 139264
//   139264 cbAf        (512 KB) -> 663552  (fp16 of -1024*cb in A-frag order)
// zq-region (32 MB) scratch:
//   [0, 16 MB)       zBf   fp16 z b-frags      (= zq batches 0..15)
//   [16 MB, 24 MB)   st4   per-(k8,px) top-4   (8 x 32768 x 32 B)
// finish gathers all batches EXCEPT 16..23 (st4 shadow); gather2 fills them.

// ---------------------------------------------------------------------------
// numpy pairwise fp32 sum of squares over 256 elements (stride in elems).
__device__ __forceinline__ float np_sumsq_256(const float* a, int stride) {
    float blk[2];
    #pragma unroll
    for (int h = 0; h < 2; ++h) {
        const float* p = a + (size_t)h * 128 * stride;
        float r[8];
        #pragma unroll
        for (int j = 0; j < 8; ++j) {
            float v = p[(size_t)j * stride];
            r[j] = __fmul_rn(v, v);
        }
        for (int i = 1; i < 16; ++i) {
            #pragma unroll
            for (int j = 0; j < 8; ++j) {
                float v = p[(size_t)(i * 8 + j) * stride];
                r[j] = __fadd_rn(r[j], __fmul_rn(v, v));
            }
        }
        blk[h] = __fadd_rn(__fadd_rn(__fadd_rn(r[0], r[1]), __fadd_rn(r[2], r[3])),
                           __fadd_rn(__fadd_rn(r[4], r[5]), __fadd_rn(r[6], r[7])));
    }
    return __fadd_rn(blk[0], blk[1]);
}

// ---------------------------------------------------------------------------
// Fused prep (unchanged, validated): bnorm+hbF(0-3) | anorm(4-131) |
// cbsplit(132-259) | zfrag(260-4355)
// ---------------------------------------------------------------------------
__global__ __launch_bounds__(256) void prep_kernel(const float* __restrict__ z,
                                                   const float* __restrict__ cb,
                                                   float* __restrict__ A32,
                                                   float* __restrict__ B32,
                                                   float* __restrict__ hbF,
                                                   half8* __restrict__ cbAf,
                                                   half8* __restrict__ zBf) {
    const int blk = blockIdx.x;
    const int tid = threadIdx.x;
    if (blk < 4) {
        int k = blk * 256 + tid;
        float v = np_sumsq_256(cb + (size_t)k * D_, 1);
        B32[k] = v;
        hbF[k] = 512.0f * v;
    } else if (blk < 132) {
        int n  = (blk - 4) * 256 + tid;
        int b  = n >> 10;
        int hw = n & 1023;
        A32[n] = np_sumsq_256(z + (size_t)b * (D_ * HW_) + hw, HW_);
    } else if (blk < 260) {
        // A-frag order: c = ((kf*8+ds)*64 + q*16 + r) holds -1024*cb[k][d0+j]
        int c  = (blk - 132) * 256 + tid;   // 0..32767
        int kf = c >> 9;
        int ds = (c >> 6) & 7;
        int q  = (c >> 4) & 3;
        int r  = c & 15;
        int k  = kf * 16 + r;
        int d0 = ds * 32 + q * 8;
        const float* src = cb + (size_t)k * D_ + d0;
        half8 v;
        #pragma unroll
        for (int j = 0; j < 8; ++j) v[j] = (_Float16)(src[j] * -1024.0f);
        cbAf[c] = v;
    } else {
        // B-frag order: c = (pxg*8+ds)*64 + lane holds z[px][d0+j] as fp16
        int c    = (blk - 260) * 256 + tid;  // 0..1048575
        int pxg  = c >> 9;
        int ds   = (c >> 6) & 7;
        int lane = c & 63;
        int q    = lane >> 4;
        int r    = lane & 15;
        int px   = pxg * 16 + r;
        int bb   = px >> 10;
        int hw   = px & 1023;
        int d0   = ds * 32 + q * 8;
        const float* src = z + (size_t)bb * (D_ * HW_) + hw;
        half8 v;
        #pragma unroll
        for (int j = 0; j < 8; ++j) v[j] = (_Float16)src[(size_t)(d0 + j) * HW_];
        zBf[c] = v;
    }
}

// lex compare-swap: keep smaller (v,k) in (va,ka)
#define CSWAP(va, ka, vb, kb) { \
    bool sw = (vb < va) || (vb == va && kb < ka); \
    float tv = va; int tk = ka; \
    va = sw ? vb : va; ka = sw ? kb : ka; \
    vb = sw ? tv : vb; kb = sw ? tk : kb; }

// sorted top-4 insert (ascending; ascending-k scan => first-occurrence ties)
#define TOP4_INS(S, KK, V0,K0,V1,K1,V2,K2,V3,K3) \
    if (S < V3) { \
        if (S < V1) { \
            V3 = V2; K3 = K2; V2 = V1; K2 = K1; \
            if (S < V0) { V1 = V0; K1 = K0; V0 = S; K0 = KK; } \
            else        { V1 = S;  K1 = KK; } \
        } else { \
            if (S < V2) { V3 = V2; K3 = K2; V2 = S; K2 = KK; } \
            else        { V3 = S;  K3 = KK; } \
        } \
    }

// merge the 4 q-lanes' sorted-4 lists (xor 16 then 32): bitonic
#define QMERGE(V0,K0,V1,K1,V2,K2,V3,K3) \
    _Pragma("unroll") \
    for (int off = 16; off <= 32; off <<= 1) { \
        float b0_ = __shfl_xor(V0, off, 64), b1_ = __shfl_xor(V1, off, 64); \
        float b2_ = __shfl_xor(V2, off, 64), b3_ = __shfl_xor(V3, off, 64); \
        int   c0_ = __shfl_xor(K0, off, 64), c1_ = __shfl_xor(K1, off, 64); \
        int   c2_ = __shfl_xor(K2, off, 64), c3_ = __shfl_xor(K3, off, 64); \
        CSWAP(V0, K0, b3_, c3_); CSWAP(V1, K1, b2_, c2_); \
        CSWAP(V2, K2, b1_, c1_); CSWAP(V3, K3, b0_, c0_); \
        CSWAP(V0, K0, V2, K2); CSWAP(V1, K1, V3, K3); \
        CSWAP(V0, K0, V1, K1); CSWAP(V2, K2, V3, K3); \
    }

// merge two sorted-4 lists (b consumed) -> sorted-4 in a
#define MERGE2(V0,K0,V1,K1,V2,K2,V3,K3, W0,P0,W1,P1,W2,P2,W3,P3) { \
    CSWAP(V0, K0, W3, P3); CSWAP(V1, K1, W2, P2); \
    CSWAP(V2, K2, W1, P1); CSWAP(V3, K3, W0, P0); \
    CSWAP(V0, K0, V2, K2); CSWAP(V1, K1, V3, K3); \
    CSWAP(V0, K0, V1, K1); CSWAP(V2, K2, V3, K3); }

// ---------------------------------------------------------------------------
// Screening v15: same K-eighths one-b-set structure as R23 but at
// __launch_bounds__(256, 6) = 85-VGPR cap. R22/R23 proved 64 VGPRs
// (256,8) forces spill (FETCH 400/98 MB); the kernel needs ~75.
// 6 waves/SIMD = 24 waves/CU, 1.5x R20's occupancy, no spill expected.
// ---------------------------------------------------------------------------
__global__ __launch_bounds__(256, 6) void vq_screen15(
        const half8* __restrict__ zBf,
        const half8* __restrict__ cbAf,
        const float* __restrict__ hbF,
        float* __restrict__ st4)
{
    __shared__ half8 abuf[2][512];    // [dbuf][8KB chunk slab] = 16 KB

    const int tid  = threadIdx.x;
    const int lane = tid & 63;
    const int wave = tid >> 6;        // 0..3
    const int q    = lane >> 4;
    const int r    = lane & 15;

    const int tile = blockIdx.x >> 3;     // 0..511 (64-px tile)
    const int k8   = blockIdx.x & 7;      // K-eighth (128 codes)

    // one register b-frag set (16 px per wave)
    const int f0 = tile * 4 + wave;
    half8 b0[8];
    #pragma unroll
    for (int ds = 0; ds < 8; ++ds)
        b0[ds] = zBf[(size_t)(f0 * 8 + ds) * 64 + lane];

    // staging: each wave stages 2KB (2 x 1KB GLDS) of the 8KB chunk slab
    const char* gbase = (const char*)cbAf + (size_t)k8 * 65536
                      + wave * 2048 + lane * 16;
    const int   ldsOff = wave * 128;   // half8 units (2 KB)

    {   // prologue: stage chunk 0 into buf 0
        char* d = (char*)&abuf[0][ldsOff];
        GLDS(gbase, d);
        GLDS(gbase + 1024, d + 1024);
    }
    __syncthreads();

    float v0 = 3.4e38f, v1 = 3.4e38f, v2 = 3.4e38f, v3 = 3.4e38f;
    int   k0 = 0x7fffffff, k1 = 0x7fffffff, k2 = 0x7fffffff, k3 = 0x7fffffff;

    for (int chl = 0; chl < 8; ++chl) {
        const int cur = chl & 1;
        if (chl < 7) {
            const char* s = gbase + (size_t)(chl + 1) * 8192;
            char* d = (char*)&abuf[cur ^ 1][ldsOff];
            GLDS(s, d);
            GLDS(s + 1024, d + 1024);
        }

        const int kbase = k8 * 128 + chl * 16;
        const float4 h = *reinterpret_cast<const float4*>(&hbF[kbase + q * 4]);
        f32x4 acc = {h.x, h.y, h.z, h.w};

        #pragma unroll
        for (int ds = 0; ds < 8; ++ds) {
            half8 A0 = abuf[cur][ds * 64 + lane];
            acc = __builtin_amdgcn_mfma_f32_16x16x32_f16(A0, b0[ds], acc, 0,0,0);
        }

        // acc IS 1024*s. min4 gate -> sorted top-4 (ascending k order kept)
        float mg = fminf(fminf(acc[0], acc[1]), fminf(acc[2], acc[3]));
        if (mg < v3) {
            #pragma unroll
            for (int i = 0; i < 4; ++i) {
                int kk  = kbase + q * 4 + i;
                float s = acc[i];
                TOP4_INS(s, kk, v0,k0, v1,k1, v2,k2, v3,k3);
            }
        }
        __syncthreads();
    }

    // merge the 4 q-lanes per pixel; q==0 lanes write st4
    QMERGE(v0,k0, v1,k1, v2,k2, v3,k3);

    if (q == 0) {
        int n = tile * 64 + wave * 16 + r;
        float* p = st4 + ((size_t)k8 * N_ + n) * 8;
        *reinterpret_cast<float4*>(p)     = make_float4(v0, v1, v2, v3);
        *reinterpret_cast<float4*>(p + 4) = make_float4(
            __int_as_float(k0), __int_as_float(k1),
            __int_as_float(k2), __int_as_float(k3));
    }
}

// ---------------------------------------------------------------------------
// Fused finish (unchanged, validated): 8-way merge + flag + in-block exact
// fp64->d32 resolution + gather (skips st4-shadowed batches 16..23).
// ---------------------------------------------------------------------------
__global__ __launch_bounds__(256) void finish_kernel(
        const float* __restrict__ st4,
        const float* __restrict__ A32,
        const float* __restrict__ B32,
        const float* __restrict__ cb,
        const float* __restrict__ z,
        float* __restrict__ oidx,
        float* __restrict__ zq)
{
    __shared__ int fcount;
    __shared__ int flist[64];
    __shared__ int fck[64][4];
    __shared__ int fidx[64];

    const int tid  = threadIdx.x;
    const int lane = tid & 63;
    const int wave = tid >> 6;
    const int p0   = blockIdx.x * 64;

    if (tid == 0) fcount = 0;
    __syncthreads();

    if (tid < 64) {
        const int n = p0 + tid;
        float V0, V1, V2, V3; int K0, K1, K2, K3;
        {
            const float* p = st4 + (size_t)n * 8;            // k8 = 0
            float4 v  = *reinterpret_cast<const float4*>(p);
            float4 kf = *reinterpret_cast<const float4*>(p + 4);
            V0 = v.x; V1 = v.y; V2 = v.z; V3 = v.w;
            K0 = __float_as_int(kf.x); K1 = __float_as_int(kf.y);
            K2 = __float_as_int(kf.z); K3 = __float_as_int(kf.w);
        }
        #pragma unroll
        for (int k8 = 1; k8 < 8; ++k8) {
            const float* p = st4 + ((size_t)k8 * N_ + n) * 8;
            float4 v  = *reinterpret_cast<const float4*>(p);
            float4 kf = *reinterpret_cast<const float4*>(p + 4);
            float W0 = v.x, W1 = v.y, W2 = v.z, W3 = v.w;
            int   P0 = __float_as_int(kf.x), P1 = __float_as_int(kf.y);
            int   P2 = __float_as_int(kf.z), P3 = __float_as_int(kf.w);
            MERGE2(V0,K0, V1,K1, V2,K2, V3,K3, W0,P0, W1,P1, W2,P2, W3,P3);
        }
        fidx[tid] = K0;
        oidx[n] = (float)K0;
        if (V1 - V0 < QMARGS) {
            int slot = atomicAdd(&fcount, 1);
            flist[slot] = tid;
            fck[slot][0] = K0; fck[slot][1] = K1;
            fck[slot][2] = K2; fck[slot][3] = K3;
        }
    }
    __syncthreads();

    const int fc = fcount;
    for (int i = wave; i < fc; i += 4) {
        const int pl = flist[i];
        const int nn = p0 + pl;
        const int bb = nn >> 10, hw = nn & 1023;
        const float* zb = z + (size_t)bb * (D_ * HW_) + hw;
        float zf[4];
        #pragma unroll
        for (int j = 0; j < 4; ++j) zf[j] = zb[(size_t)(lane * 4 + j) * HW_];

        const float An = A32[nn];
        float bd = 3.4e38f;
        int   bk = 0x7fffffff;
        #pragma unroll
        for (int c = 0; c < 4; ++c) {
            int k = fck[i][c];
            float4 c4 = *reinterpret_cast<const float4*>(cb + (size_t)k * D_ + lane * 4);
            double acc = 0.0;
            acc = fma((double)c4.x, (double)zf[0], acc);
            acc = fma((double)c4.y, (double)zf[1], acc);
            acc = fma((double)c4.z, (double)zf[2], acc);
            acc = fma((double)c4.w, (double)zf[3], acc);
            #pragma unroll
            for (int off = 1; off <= 32; off <<= 1) acc += __shfl_xor(acc, off, 64);
            float C32 = (float)acc;
            float d32 = __fsub_rn(__fadd_rn(An, B32[k]), __fadd_rn(C32, C32));
            if (d32 < bd || (d32 == bd && k < bk)) { bd = d32; bk = k; }
        }
        if (lane == 0) { oidx[nn] = (float)bk; fidx[pl] = bk; }
    }
    __syncthreads();

    if (p0 >= 16384 && p0 < 24576) return;
    const int s_nl = tid & 63;
    const int s_dw = tid >> 6;
    const int b    = p0 >> 10;
    const int hw0  = p0 & 1023;
    const int idxn = fidx[s_nl];
    const float4* crow = reinterpret_cast<const float4*>(cb + (size_t)idxn * D_);
    float* zqb = zq + (size_t)b * (D_ * HW_) + hw0;
    #pragma unroll
    for (int rr = 0; rr < 16; ++rr) {
        int d4 = s_dw * 16 + rr;
        float4 c4 = crow[d4];
        int d = d4 * 4;
        zqb[(size_t)(d + 0) * HW_ + s_nl] = c4.x;
        zqb[(size_t)(d + 1) * HW_ + s_nl] = c4.y;
        zqb[(size_t)(d + 2) * HW_ + s_nl] = c4.z;
        zqb[(size_t)(d + 3) * HW_ + s_nl] = c4.w;
    }
}

// ---------------------------------------------------------------------------
__global__ __launch_bounds__(256) void gather2_kernel(const float* __restrict__ cb,
                                                      const float* __restrict__ oidx,
                                                      float* __restrict__ zq,
                                                      int base) {
    const int tid  = threadIdx.x;
    const int s_nl = tid & 63;
    const int s_dw = tid >> 6;
    const int p0   = base + blockIdx.x * 64;
    const int b    = p0 >> 10;
    const int hw0  = p0 & 1023;

    int idxn = (int)oidx[p0 + s_nl];
    const float4* crow = reinterpret_cast<const float4*>(cb + (size_t)idxn * D_);
    float* zqb = zq + (size_t)b * (D_ * HW_) + hw0;
    #pragma unroll
    for (int r = 0; r < 16; ++r) {
        int d4 = s_dw * 16 + r;
        float4 c4 = crow[d4];
        int d = d4 * 4;
        zqb[(size_t)(d + 0) * HW_ + s_nl] = c4.x;
        zqb[(size_t)(d + 1) * HW_ + s_nl] = c4.y;
        zqb[(size_t)(d + 2) * HW_ + s_nl] = c4.z;
        zqb[(size_t)(d + 3) * HW_ + s_nl] = c4.w;
    }
}

extern "C" void kernel_launch(void* const* d_in, const int* in_sizes, int n_in,
                              void* d_out, int out_size, void* d_ws, size_t ws_size,
                              hipStream_t stream) {
    const float* z  = (const float*)d_in[0];   // [32,256,32,32] fp32
    const float* cb = (const float*)d_in[1];   // [1024,256] fp32

    float* zq   = (float*)d_out;
    float* oidx = zq + (size_t)N_ * D_;        // byte 33554432

    char* ws = (char*)d_ws;
    float* B32  = (float*)(ws + 0);
    float* hbF  = (float*)(ws + 4096);
    float* A32  = (float*)(ws + 8192);
    half8* cbAf = (half8*)(ws + 139264);       // ends 663552

    // zq-region scratch: zBf [0,16MB), st4 [16MB,24MB)
    char*  zqb = (char*)zq;
    half8* zBf = (half8*)zqb;                  // 16 MB
    float* st4 = (float*)(zqb + 16777216);     // 8 MB (= batches 16..23)

    prep_kernel<<<4356, 256, 0, stream>>>(z, cb, A32, B32, hbF, cbAf, zBf);
    vq_screen15<<<4096, 256, 0, stream>>>(zBf, cbAf, hbF, st4);
    finish_kernel<<<N_ / 64, 256, 0, stream>>>(st4, A32, B32, cb, z, oidx, zq);
    gather2_kernel<<<128, 256, 0, stream>>>(cb, oidx, zq, 16384);
}

// Round 25
// 92.037 us; speedup vs baseline: 2.1458x; 1.0739x over previous
//
#include <hip/hip_runtime.h>

#define D_   256
#define HW_  1024
#define N_   32768
#define K_   1024

#define QMARGS 0.12288f   // flag margin in SCALED (1024*s) units = 1.2e-4 s-units

typedef _Float16 half8 __attribute__((ext_vector_type(8)));     // 8 fp16 (4 VGPRs)
typedef __attribute__((ext_vector_type(4))) float f32x4;        // MFMA acc

#define GLDS(g, l) __builtin_amdgcn_global_load_lds( \
    (const __attribute__((address_space(1))) unsigned int*)(g), \
    (__attribute__((address_space(3))) unsigned int*)(l), 16, 0, 0)

// ws layout (bytes):
//   0      B32[1024]   (4 KB)   -> 4096
//   4096   hbF[1024]   (4 KB)   -> 8192   = 512*B32 (scaled acc-init table)
//   8192   A32[32768]  (128 KB) -> 139264
//   139264 cbAf        (512 KB) -> 663552  (fp16 of -1024*cb in A-frag order)
// zq-region (32 MB) scratch:
//   [0, 16 MB)       zBf   fp16 z b-frags      (= zq batches 0..15)
//   [16 MB, 24 MB)   st4   per-(k8,px) top-4   (8 x 32768 x 32 B)
// finish gathers all batches EXCEPT 16..23 (st4 shadow); gather2 fills them.

// ---------------------------------------------------------------------------
// numpy pairwise fp32 sum of squares over 256 elements (stride in elems).
__device__ __forceinline__ float np_sumsq_256(const float* a, int stride) {
    float blk[2];
    #pragma unroll
    for (int h = 0; h < 2; ++h) {
        const float* p = a + (size_t)h * 128 * stride;
        float r[8];
        #pragma unroll
        for (int j = 0; j < 8; ++j) {
            float v = p[(size_t)j * stride];
            r[j] = __fmul_rn(v, v);
        }
        for (int i = 1; i < 16; ++i) {
            #pragma unroll
            for (int j = 0; j < 8; ++j) {
                float v = p[(size_t)(i * 8 + j) * stride];
                r[j] = __fadd_rn(r[j], __fmul_rn(v, v));
            }
        }
        blk[h] = __fadd_rn(__fadd_rn(__fadd_rn(r[0], r[1]), __fadd_rn(r[2], r[3])),
                           __fadd_rn(__fadd_rn(r[4], r[5]), __fadd_rn(r[6], r[7])));
    }
    return __fadd_rn(blk[0], blk[1]);
}

// ---------------------------------------------------------------------------
// Fused prep (unchanged, validated): bnorm+hbF(0-3) | anorm(4-131) |
// cbsplit(132-259) | zfrag(260-4355)
// ---------------------------------------------------------------------------
__global__ __launch_bounds__(256) void prep_kernel(const float* __restrict__ z,
                                                   const float* __restrict__ cb,
                                                   float* __restrict__ A32,
                                                   float* __restrict__ B32,
                                                   float* __restrict__ hbF,
                                                   half8* __restrict__ cbAf,
                                                   half8* __restrict__ zBf) {
    const int blk = blockIdx.x;
    const int tid = threadIdx.x;
    if (blk < 4) {
        int k = blk * 256 + tid;
        float v = np_sumsq_256(cb + (size_t)k * D_, 1);
        B32[k] = v;
        hbF[k] = 512.0f * v;
    } else if (blk < 132) {
        int n  = (blk - 4) * 256 + tid;
        int b  = n >> 10;
        int hw = n & 1023;
        A32[n] = np_sumsq_256(z + (size_t)b * (D_ * HW_) + hw, HW_);
    } else if (blk < 260) {
        // A-frag order: c = ((kf*8+ds)*64 + q*16 + r) holds -1024*cb[k][d0+j]
        int c  = (blk - 132) * 256 + tid;   // 0..32767
        int kf = c >> 9;
        int ds = (c >> 6) & 7;
        int q  = (c >> 4) & 3;
        int r  = c & 15;
        int k  = kf * 16 + r;
        int d0 = ds * 32 + q * 8;
        const float* src = cb + (size_t)k * D_ + d0;
        half8 v;
        #pragma unroll
        for (int j = 0; j < 8; ++j) v[j] = (_Float16)(src[j] * -1024.0f);
        cbAf[c] = v;
    } else {
        // B-frag order: c = (pxg*8+ds)*64 + lane holds z[px][d0+j] as fp16
        int c    = (blk - 260) * 256 + tid;  // 0..1048575
        int pxg  = c >> 9;
        int ds   = (c >> 6) & 7;
        int lane = c & 63;
        int q    = lane >> 4;
        int r    = lane & 15;
        int px   = pxg * 16 + r;
        int bb   = px >> 10;
        int hw   = px & 1023;
        int d0   = ds * 32 + q * 8;
        const float* src = z + (size_t)bb * (D_ * HW_) + hw;
        half8 v;
        #pragma unroll
        for (int j = 0; j < 8; ++j) v[j] = (_Float16)src[(size_t)(d0 + j) * HW_];
        zBf[c] = v;
    }
}

// lex compare-swap: keep smaller (v,k) in (va,ka)
#define CSWAP(va, ka, vb, kb) { \
    bool sw = (vb < va) || (vb == va && kb < ka); \
    float tv = va; int tk = ka; \
    va = sw ? vb : va; ka = sw ? kb : ka; \
    vb = sw ? tv : vb; kb = sw ? tk : kb; }

// sorted top-4 insert (ascending; ascending-k scan => first-occurrence ties)
#define TOP4_INS(S, KK, V0,K0,V1,K1,V2,K2,V3,K3) \
    if (S < V3) { \
        if (S < V1) { \
            V3 = V2; K3 = K2; V2 = V1; K2 = K1; \
            if (S < V0) { V1 = V0; K1 = K0; V0 = S; K0 = KK; } \
            else        { V1 = S;  K1 = KK; } \
        } else { \
            if (S < V2) { V3 = V2; K3 = K2; V2 = S; K2 = KK; } \
            else        { V3 = S;  K3 = KK; } \
        } \
    }

// merge the 4 q-lanes' sorted-4 lists (xor 16 then 32): bitonic
#define QMERGE(V0,K0,V1,K1,V2,K2,V3,K3) \
    _Pragma("unroll") \
    for (int off = 16; off <= 32; off <<= 1) { \
        float b0_ = __shfl_xor(V0, off, 64), b1_ = __shfl_xor(V1, off, 64); \
        float b2_ = __shfl_xor(V2, off, 64), b3_ = __shfl_xor(V3, off, 64); \
        int   c0_ = __shfl_xor(K0, off, 64), c1_ = __shfl_xor(K1, off, 64); \
        int   c2_ = __shfl_xor(K2, off, 64), c3_ = __shfl_xor(K3, off, 64); \
        CSWAP(V0, K0, b3_, c3_); CSWAP(V1, K1, b2_, c2_); \
        CSWAP(V2, K2, b1_, c1_); CSWAP(V3, K3, b0_, c0_); \
        CSWAP(V0, K0, V2, K2); CSWAP(V1, K1, V3, K3); \
        CSWAP(V0, K0, V1, K1); CSWAP(V2, K2, V3, K3); \
    }

// merge two sorted-4 lists (b consumed) -> sorted-4 in a
#define MERGE2(V0,K0,V1,K1,V2,K2,V3,K3, W0,P0,W1,P1,W2,P2,W3,P3) { \
    CSWAP(V0, K0, W3, P3); CSWAP(V1, K1, W2, P2); \
    CSWAP(V2, K2, W1, P1); CSWAP(V3, K3, W0, P0); \
    CSWAP(V0, K0, V2, K2); CSWAP(V1, K1, V3, K3); \
    CSWAP(V0, K0, V1, K1); CSWAP(V2, K2, V3, K3); }

// ---------------------------------------------------------------------------
// Screening v16: R24's v15 + XCD-AWARE BLOCK DECODE. Old decode put a tile's
// 8 k8-blocks on 8 different XCDs (id%8 round-robin) -> zB frags re-fetched
// 8x from L3/HBM (FETCH 66 MB). New decode: x=id&7, g=id>>3, tile=x*64+(g>>3),
// k8=g&7  => same-tile blocks share an XCD (= tile>>6 mod 8) and sit 8 ids
// apart (co-dispatched) -> 7 of 8 zB reads become L2 hits. Bijective; work
// per (tile,k8) unchanged -> outputs bit-identical.
// ---------------------------------------------------------------------------
__global__ __launch_bounds__(256, 6) void vq_screen16(
        const half8* __restrict__ zBf,
        const half8* __restrict__ cbAf,
        const float* __restrict__ hbF,
        float* __restrict__ st4)
{
    __shared__ half8 abuf[2][512];    // [dbuf][8KB chunk slab] = 16 KB

    const int tid  = threadIdx.x;
    const int lane = tid & 63;
    const int wave = tid >> 6;        // 0..3
    const int q    = lane >> 4;
    const int r    = lane & 15;

    // XCD-aware decode (see header comment)
    const int x    = blockIdx.x & 7;
    const int g    = blockIdx.x >> 3;
    const int tile = x * 64 + (g >> 3);   // 0..511 (64-px tile)
    const int k8   = g & 7;               // K-eighth (128 codes)

    // one register b-frag set (16 px per wave)
    const int f0 = tile * 4 + wave;
    half8 b0[8];
    #pragma unroll
    for (int ds = 0; ds < 8; ++ds)
        b0[ds] = zBf[(size_t)(f0 * 8 + ds) * 64 + lane];

    // staging: each wave stages 2KB (2 x 1KB GLDS) of the 8KB chunk slab
    const char* gbase = (const char*)cbAf + (size_t)k8 * 65536
                      + wave * 2048 + lane * 16;
    const int   ldsOff = wave * 128;   // half8 units (2 KB)

    {   // prologue: stage chunk 0 into buf 0
        char* d = (char*)&abuf[0][ldsOff];
        GLDS(gbase, d);
        GLDS(gbase + 1024, d + 1024);
    }
    __syncthreads();

    float v0 = 3.4e38f, v1 = 3.4e38f, v2 = 3.4e38f, v3 = 3.4e38f;
    int   k0 = 0x7fffffff, k1 = 0x7fffffff, k2 = 0x7fffffff, k3 = 0x7fffffff;

    for (int chl = 0; chl < 8; ++chl) {
        const int cur = chl & 1;
        if (chl < 7) {
            const char* s = gbase + (size_t)(chl + 1) * 8192;
            char* d = (char*)&abuf[cur ^ 1][ldsOff];
            GLDS(s, d);
            GLDS(s + 1024, d + 1024);
        }

        const int kbase = k8 * 128 + chl * 16;
        const float4 h = *reinterpret_cast<const float4*>(&hbF[kbase + q * 4]);
        f32x4 acc = {h.x, h.y, h.z, h.w};

        #pragma unroll
        for (int ds = 0; ds < 8; ++ds) {
            half8 A0 = abuf[cur][ds * 64 + lane];
            acc = __builtin_amdgcn_mfma_f32_16x16x32_f16(A0, b0[ds], acc, 0,0,0);
        }

        // acc IS 1024*s. min4 gate -> sorted top-4 (ascending k order kept)
        float mg = fminf(fminf(acc[0], acc[1]), fminf(acc[2], acc[3]));
        if (mg < v3) {
            #pragma unroll
            for (int i = 0; i < 4; ++i) {
                int kk  = kbase + q * 4 + i;
                float s = acc[i];
                TOP4_INS(s, kk, v0,k0, v1,k1, v2,k2, v3,k3);
            }
        }
        __syncthreads();
    }

    // merge the 4 q-lanes per pixel; q==0 lanes write st4
    QMERGE(v0,k0, v1,k1, v2,k2, v3,k3);

    if (q == 0) {
        int n = tile * 64 + wave * 16 + r;
        float* p = st4 + ((size_t)k8 * N_ + n) * 8;
        *reinterpret_cast<float4*>(p)     = make_float4(v0, v1, v2, v3);
        *reinterpret_cast<float4*>(p + 4) = make_float4(
            __int_as_float(k0), __int_as_float(k1),
            __int_as_float(k2), __int_as_float(k3));
    }
}

// ---------------------------------------------------------------------------
// Fused finish (unchanged, validated): 8-way merge + flag + in-block exact
// fp64->d32 resolution + gather (skips st4-shadowed batches 16..23).
// ---------------------------------------------------------------------------
__global__ __launch_bounds__(256) void finish_kernel(
        const float* __restrict__ st4,
        const float* __restrict__ A32,
        const float* __restrict__ B32,
        const float* __restrict__ cb,
        const float* __restrict__ z,
        float* __restrict__ oidx,
        float* __restrict__ zq)
{
    __shared__ int fcount;
    __shared__ int flist[64];
    __shared__ int fck[64][4];
    __shared__ int fidx[64];

    const int tid  = threadIdx.x;
    const int lane = tid & 63;
    const int wave = tid >> 6;
    const int p0   = blockIdx.x * 64;

    if (tid == 0) fcount = 0;
    __syncthreads();

    if (tid < 64) {
        const int n = p0 + tid;
        float V0, V1, V2, V3; int K0, K1, K2, K3;
        {
            const float* p = st4 + (size_t)n * 8;            // k8 = 0
            float4 v  = *reinterpret_cast<const float4*>(p);
            float4 kf = *reinterpret_cast<const float4*>(p + 4);
            V0 = v.x; V1 = v.y; V2 = v.z; V3 = v.w;
            K0 = __float_as_int(kf.x); K1 = __float_as_int(kf.y);
            K2 = __float_as_int(kf.z); K3 = __float_as_int(kf.w);
        }
        #pragma unroll
        for (int k8 = 1; k8 < 8; ++k8) {
            const float* p = st4 + ((size_t)k8 * N_ + n) * 8;
            float4 v  = *reinterpret_cast<const float4*>(p);
            float4 kf = *reinterpret_cast<const float4*>(p + 4);
            float W0 = v.x, W1 = v.y, W2 = v.z, W3 = v.w;
            int   P0 = __float_as_int(kf.x), P1 = __float_as_int(kf.y);
            int   P2 = __float_as_int(kf.z), P3 = __float_as_int(kf.w);
            MERGE2(V0,K0, V1,K1, V2,K2, V3,K3, W0,P0, W1,P1, W2,P2, W3,P3);
        }
        fidx[tid] = K0;
        oidx[n] = (float)K0;
        if (V1 - V0 < QMARGS) {
            int slot = atomicAdd(&fcount, 1);
            flist[slot] = tid;
            fck[slot][0] = K0; fck[slot][1] = K1;
            fck[slot][2] = K2; fck[slot][3] = K3;
        }
    }
    __syncthreads();

    const int fc = fcount;
    for (int i = wave; i < fc; i += 4) {
        const int pl = flist[i];
        const int nn = p0 + pl;
        const int bb = nn >> 10, hw = nn & 1023;
        const float* zb = z + (size_t)bb * (D_ * HW_) + hw;
        float zf[4];
        #pragma unroll
        for (int j = 0; j < 4; ++j) zf[j] = zb[(size_t)(lane * 4 + j) * HW_];

        const float An = A32[nn];
        float bd = 3.4e38f;
        int   bk = 0x7fffffff;
        #pragma unroll
        for (int c = 0; c < 4; ++c) {
            int k = fck[i][c];
            float4 c4 = *reinterpret_cast<const float4*>(cb + (size_t)k * D_ + lane * 4);
            double acc = 0.0;
            acc = fma((double)c4.x, (double)zf[0], acc);
            acc = fma((double)c4.y, (double)zf[1], acc);
            acc = fma((double)c4.z, (double)zf[2], acc);
            acc = fma((double)c4.w, (double)zf[3], acc);
            #pragma unroll
            for (int off = 1; off <= 32; off <<= 1) acc += __shfl_xor(acc, off, 64);
            float C32 = (float)acc;
            float d32 = __fsub_rn(__fadd_rn(An, B32[k]), __fadd_rn(C32, C32));
            if (d32 < bd || (d32 == bd && k < bk)) { bd = d32; bk = k; }
        }
        if (lane == 0) { oidx[nn] = (float)bk; fidx[pl] = bk; }
    }
    __syncthreads();

    if (p0 >= 16384 && p0 < 24576) return;
    const int s_nl = tid & 63;
    const int s_dw = tid >> 6;
    const int b    = p0 >> 10;
    const int hw0  = p0 & 1023;
    const int idxn = fidx[s_nl];
    const float4* crow = reinterpret_cast<const float4*>(cb + (size_t)idxn * D_);
    float* zqb = zq + (size_t)b * (D_ * HW_) + hw0;
    #pragma unroll
    for (int rr = 0; rr < 16; ++rr) {
        int d4 = s_dw * 16 + rr;
        float4 c4 = crow[d4];
        int d = d4 * 4;
        zqb[(size_t)(d + 0) * HW_ + s_nl] = c4.x;
        zqb[(size_t)(d + 1) * HW_ + s_nl] = c4.y;
        zqb[(size_t)(d + 2) * HW_ + s_nl] = c4.z;
        zqb[(size_t)(d + 3) * HW_ + s_nl] = c4.w;
    }
}

// ---------------------------------------------------------------------------
__global__ __launch_bounds__(256) void gather2_kernel(const float* __restrict__ cb,
                                                      const float* __restrict__ oidx,
                                                      float* __restrict__ zq,
                                                      int base) {
    const int tid  = threadIdx.x;
    const int s_nl = tid & 63;
    const int s_dw = tid >> 6;
    const int p0   = base + blockIdx.x * 64;
    const int b    = p0 >> 10;
    const int hw0  = p0 & 1023;

    int idxn = (int)oidx[p0 + s_nl];
    const float4* crow = reinterpret_cast<const float4*>(cb + (size_t)idxn * D_);
    float* zqb = zq + (size_t)b * (D_ * HW_) + hw0;
    #pragma unroll
    for (int r = 0; r < 16; ++r) {
        int d4 = s_dw * 16 + r;
        float4 c4 = crow[d4];
        int d = d4 * 4;
        zqb[(size_t)(d + 0) * HW_ + s_nl] = c4.x;
        zqb[(size_t)(d + 1) * HW_ + s_nl] = c4.y;
        zqb[(size_t)(d + 2) * HW_ + s_nl] = c4.z;
        zqb[(size_t)(d + 3) * HW_ + s_nl] = c4.w;
    }
}

extern "C" void kernel_launch(void* const* d_in, const int* in_sizes, int n_in,
                              void* d_out, int out_size, void* d_ws, size_t ws_size,
                              hipStream_t stream) {
    const float* z  = (const float*)d_in[0];   // [32,256,32,32] fp32
    const float* cb = (const float*)d_in[1];   // [1024,256] fp32

    float* zq   = (float*)d_out;
    float* oidx = zq + (size_t)N_ * D_;        // byte 33554432

    char* ws = (char*)d_ws;
    float* B32  = (float*)(ws + 0);
    float* hbF  = (float*)(ws + 4096);
    float* A32  = (float*)(ws + 8192);
    half8* cbAf = (half8*)(ws + 139264);       // ends 663552

    // zq-region scratch: zBf [0,16MB), st4 [16MB,24MB)
    char*  zqb = (char*)zq;
    half8* zBf = (half8*)zqb;                  // 16 MB
    float* st4 = (float*)(zqb + 16777216);     // 8 MB (= batches 16..23)

    prep_kernel<<<4356, 256, 0, stream>>>(z, cb, A32, B32, hbF, cbAf, zBf);
    vq_screen16<<<4096, 256, 0, stream>>>(zBf, cbAf, hbF, st4);
    finish_kernel<<<N_ / 64, 256, 0, stream>>>(st4, A32, B32, cb, z, oidx, zq);
    gather2_kernel<<<128, 256, 0, stream>>>(cb, oidx, zq, 16384);
}

// Round 26
// 76.728 us; speedup vs baseline: 2.5739x; 1.1995x over previous
//
#include <hip/hip_runtime.h>

#define D_   256
#define HW_  1024
#define N_   32768
#define K_   1024

#define QMARGS 0.12288f   // flag margin in SCALED (1024*s) units = 1.2e-4 s-units

typedef _Float16 half8 __attribute__((ext_vector_type(8)));     // 8 fp16 (4 VGPRs)
typedef __attribute__((ext_vector_type(4))) float f32x4;        // MFMA acc

#define GLDS(g, l) __builtin_amdgcn_global_load_lds( \
    (const __attribute__((address_space(1))) unsigned int*)(g), \
    (__attribute__((address_space(3))) unsigned int*)(l), 16, 0, 0)

// ws layout (bytes):
//   0      B32[1024]   (4 KB)   -> 4096
//   4096   hbF[1024]   (4 KB)   -> 8192   = 512*B32 (scaled acc-init table)
//   8192   A32[32768]  (128 KB) -> 139264
//   139264 cbAf        (512 KB) -> 663552  (fp16 of -1024*cb in A-frag order)
//   [663552 .. +8 MB)  st4     IF ws_size >= 9052160 (else st4 shadows zq)
// zq-region (32 MB) scratch:
//   [0, 16 MB)       zBf   fp16 z b-frags      (= zq batches 0..15)
//   [16 MB, 24 MB)   st4   (fallback only; finish then skips batches 16..23)

// ---------------------------------------------------------------------------
// numpy pairwise fp32 sum of squares over 256 elements (stride in elems).
__device__ __forceinline__ float np_sumsq_256(const float* a, int stride) {
    float blk[2];
    #pragma unroll
    for (int h = 0; h < 2; ++h) {
        const float* p = a + (size_t)h * 128 * stride;
        float r[8];
        #pragma unroll
        for (int j = 0; j < 8; ++j) {
            float v = p[(size_t)j * stride];
            r[j] = __fmul_rn(v, v);
        }
        for (int i = 1; i < 16; ++i) {
            #pragma unroll
            for (int j = 0; j < 8; ++j) {
                float v = p[(size_t)(i * 8 + j) * stride];
                r[j] = __fadd_rn(r[j], __fmul_rn(v, v));
            }
        }
        blk[h] = __fadd_rn(__fadd_rn(__fadd_rn(r[0], r[1]), __fadd_rn(r[2], r[3])),
                           __fadd_rn(__fadd_rn(r[4], r[5]), __fadd_rn(r[6], r[7])));
    }
    return __fadd_rn(blk[0], blk[1]);
}

// ---------------------------------------------------------------------------
// Fused prep v2: bnorm+hbF(0-3) | cbsplit(4-131) | zfused(132-2179).
// zfused reads z ONCE: stage z[16 px][256 d] in LDS -> A32 (threads 0-15,
// bit-identical np_sumsq order) + all 512 b-frag chunks of the px-group.
// ---------------------------------------------------------------------------
__global__ __launch_bounds__(256) void prep_kernel(const float* __restrict__ z,
                                                   const float* __restrict__ cb,
                                                   float* __restrict__ A32,
                                                   float* __restrict__ B32,
                                                   float* __restrict__ hbF,
                                                   half8* __restrict__ cbAf,
                                                   half8* __restrict__ zBf) {
    const int blk = blockIdx.x;
    const int tid = threadIdx.x;
    if (blk < 4) {
        int k = blk * 256 + tid;
        float v = np_sumsq_256(cb + (size_t)k * D_, 1);
        B32[k] = v;
        hbF[k] = 512.0f * v;
    } else if (blk < 132) {
        // A-frag order: c = ((kf*8+ds)*64 + q*16 + r) holds -1024*cb[k][d0+j]
        int c  = (blk - 4) * 256 + tid;     // 0..32767
        int kf = c >> 9;
        int ds = (c >> 6) & 7;
        int q  = (c >> 4) & 3;
        int r  = c & 15;
        int k  = kf * 16 + r;
        int d0 = ds * 32 + q * 8;
        const float* src = cb + (size_t)k * D_ + d0;
        half8 v;
        #pragma unroll
        for (int j = 0; j < 8; ++j) v[j] = (_Float16)(src[j] * -1024.0f);
        cbAf[c] = v;
    } else {
        // zfused: one 16-px group per block; z read once via LDS
        __shared__ float zt[16][257];     // 16.4 KB
        const int pxg = blk - 132;        // 0..2047
        const int px0 = pxg * 16;         // 16 consecutive px, same batch
        const int bb  = px0 >> 10;
        const int hw0 = px0 & 1023;
        const float* zb = z + (size_t)bb * (D_ * HW_) + hw0;

        // stage: thread (r = tid&15, dg = tid>>4) reads d = j*16 + dg
        {
            const int r  = tid & 15;
            const int dg = tid >> 4;
            #pragma unroll
            for (int j = 0; j < 16; ++j) {
                int d = j * 16 + dg;
                zt[r][d] = zb[(size_t)d * HW_ + r];
            }
        }
        __syncthreads();

        // A32: bit-identical pairwise sum over LDS row (stride 1, d ascending)
        if (tid < 16) A32[px0 + tid] = np_sumsq_256(&zt[tid][0], 1);

        // b-frag chunks: c_local = ds*64 + lane (512 per group, 2 per thread)
        #pragma unroll
        for (int h = 0; h < 2; ++h) {
            int cl   = h * 256 + tid;     // 0..511
            int ds   = cl >> 6;
            int lane = cl & 63;
            int q    = lane >> 4;
            int rr   = lane & 15;
            int d0   = ds * 32 + q * 8;
            half8 v;
            #pragma unroll
            for (int j = 0; j < 8; ++j) v[j] = (_Float16)zt[rr][d0 + j];
            zBf[(size_t)pxg * 512 + cl] = v;
        }
    }
}

// lex compare-swap: keep smaller (v,k) in (va,ka)
#define CSWAP(va, ka, vb, kb) { \
    bool sw = (vb < va) || (vb == va && kb < ka); \
    float tv = va; int tk = ka; \
    va = sw ? vb : va; ka = sw ? kb : ka; \
    vb = sw ? tv : vb; kb = sw ? tk : kb; }

// sorted top-4 insert (ascending; ascending-k scan => first-occurrence ties)
#define TOP4_INS(S, KK, V0,K0,V1,K1,V2,K2,V3,K3) \
    if (S < V3) { \
        if (S < V1) { \
            V3 = V2; K3 = K2; V2 = V1; K2 = K1; \
            if (S < V0) { V1 = V0; K1 = K0; V0 = S; K0 = KK; } \
            else        { V1 = S;  K1 = KK; } \
        } else { \
            if (S < V2) { V3 = V2; K3 = K2; V2 = S; K2 = KK; } \
            else        { V3 = S;  K3 = KK; } \
        } \
    }

// merge the 4 q-lanes' sorted-4 lists (xor 16 then 32): bitonic
#define QMERGE(V0,K0,V1,K1,V2,K2,V3,K3) \
    _Pragma("unroll") \
    for (int off = 16; off <= 32; off <<= 1) { \
        float b0_ = __shfl_xor(V0, off, 64), b1_ = __shfl_xor(V1, off, 64); \
        float b2_ = __shfl_xor(V2, off, 64), b3_ = __shfl_xor(V3, off, 64); \
        int   c0_ = __shfl_xor(K0, off, 64), c1_ = __shfl_xor(K1, off, 64); \
        int   c2_ = __shfl_xor(K2, off, 64), c3_ = __shfl_xor(K3, off, 64); \
        CSWAP(V0, K0, b3_, c3_); CSWAP(V1, K1, b2_, c2_); \
        CSWAP(V2, K2, b1_, c1_); CSWAP(V3, K3, b0_, c0_); \
        CSWAP(V0, K0, V2, K2); CSWAP(V1, K1, V3, K3); \
        CSWAP(V0, K0, V1, K1); CSWAP(V2, K2, V3, K3); \
    }

// merge two sorted-4 lists (b consumed) -> sorted-4 in a
#define MERGE2(V0,K0,V1,K1,V2,K2,V3,K3, W0,P0,W1,P1,W2,P2,W3,P3) { \
    CSWAP(V0, K0, W3, P3); CSWAP(V1, K1, W2, P2); \
    CSWAP(V2, K2, W1, P1); CSWAP(V3, K3, W0, P0); \
    CSWAP(V0, K0, V2, K2); CSWAP(V1, K1, V3, K3); \
    CSWAP(V0, K0, V1, K1); CSWAP(V2, K2, V3, K3); }

// ---------------------------------------------------------------------------
// Screening v16 (unchanged from R25, validated): K-eighths, one b-set,
// (256,6), XCD-aware decode (same-tile k8-blocks share an XCD).
// ---------------------------------------------------------------------------
__global__ __launch_bounds__(256, 6) void vq_screen16(
        const half8* __restrict__ zBf,
        const half8* __restrict__ cbAf,
        const float* __restrict__ hbF,
        float* __restrict__ st4)
{
    __shared__ half8 abuf[2][512];    // [dbuf][8KB chunk slab] = 16 KB

    const int tid  = threadIdx.x;
    const int lane = tid & 63;
    const int wave = tid >> 6;        // 0..3
    const int q    = lane >> 4;
    const int r    = lane & 15;

    const int x    = blockIdx.x & 7;
    const int g    = blockIdx.x >> 3;
    const int tile = x * 64 + (g >> 3);   // 0..511 (64-px tile)
    const int k8   = g & 7;               // K-eighth (128 codes)

    const int f0 = tile * 4 + wave;
    half8 b0[8];
    #pragma unroll
    for (int ds = 0; ds < 8; ++ds)
        b0[ds] = zBf[(size_t)(f0 * 8 + ds) * 64 + lane];

    const char* gbase = (const char*)cbAf + (size_t)k8 * 65536
                      + wave * 2048 + lane * 16;
    const int   ldsOff = wave * 128;   // half8 units (2 KB)

    {
        char* d = (char*)&abuf[0][ldsOff];
        GLDS(gbase, d);
        GLDS(gbase + 1024, d + 1024);
    }
    __syncthreads();

    float v0 = 3.4e38f, v1 = 3.4e38f, v2 = 3.4e38f, v3 = 3.4e38f;
    int   k0 = 0x7fffffff, k1 = 0x7fffffff, k2 = 0x7fffffff, k3 = 0x7fffffff;

    for (int chl = 0; chl < 8; ++chl) {
        const int cur = chl & 1;
        if (chl < 7) {
            const char* s = gbase + (size_t)(chl + 1) * 8192;
            char* d = (char*)&abuf[cur ^ 1][ldsOff];
            GLDS(s, d);
            GLDS(s + 1024, d + 1024);
        }

        const int kbase = k8 * 128 + chl * 16;
        const float4 h = *reinterpret_cast<const float4*>(&hbF[kbase + q * 4]);
        f32x4 acc = {h.x, h.y, h.z, h.w};

        #pragma unroll
        for (int ds = 0; ds < 8; ++ds) {
            half8 A0 = abuf[cur][ds * 64 + lane];
            acc = __builtin_amdgcn_mfma_f32_16x16x32_f16(A0, b0[ds], acc, 0,0,0);
        }

        float mg = fminf(fminf(acc[0], acc[1]), fminf(acc[2], acc[3]));
        if (mg < v3) {
            #pragma unroll
            for (int i = 0; i < 4; ++i) {
                int kk  = kbase + q * 4 + i;
                float s = acc[i];
                TOP4_INS(s, kk, v0,k0, v1,k1, v2,k2, v3,k3);
            }
        }
        __syncthreads();
    }

    QMERGE(v0,k0, v1,k1, v2,k2, v3,k3);

    if (q == 0) {
        int n = tile * 64 + wave * 16 + r;
        float* p = st4 + ((size_t)k8 * N_ + n) * 8;
        *reinterpret_cast<float4*>(p)     = make_float4(v0, v1, v2, v3);
        *reinterpret_cast<float4*>(p + 4) = make_float4(
            __int_as_float(k0), __int_as_float(k1),
            __int_as_float(k2), __int_as_float(k3));
    }
}

// ---------------------------------------------------------------------------
// Fused finish (logic unchanged): 8-way merge + flag + in-block exact
// fp64->d32 resolution + gather. shadow=1 -> skip zq batches 16..23
// (st4 lives there; gather2 fills them). shadow=0 -> gather everything.
// ---------------------------------------------------------------------------
__global__ __launch_bounds__(256) void finish_kernel(
        const float* __restrict__ st4,
        const float* __restrict__ A32,
        const float* __restrict__ B32,
        const float* __restrict__ cb,
        const float* __restrict__ z,
        float* __restrict__ oidx,
        float* __restrict__ zq,
        int shadow)
{
    __shared__ int fcount;
    __shared__ int flist[64];
    __shared__ int fck[64][4];
    __shared__ int fidx[64];

    const int tid  = threadIdx.x;
    const int lane = tid & 63;
    const int wave = tid >> 6;
    const int p0   = blockIdx.x * 64;

    if (tid == 0) fcount = 0;
    __syncthreads();

    if (tid < 64) {
        const int n = p0 + tid;
        float V0, V1, V2, V3; int K0, K1, K2, K3;
        {
            const float* p = st4 + (size_t)n * 8;            // k8 = 0
            float4 v  = *reinterpret_cast<const float4*>(p);
            float4 kf = *reinterpret_cast<const float4*>(p + 4);
            V0 = v.x; V1 = v.y; V2 = v.z; V3 = v.w;
            K0 = __float_as_int(kf.x); K1 = __float_as_int(kf.y);
            K2 = __float_as_int(kf.z); K3 = __float_as_int(kf.w);
        }
        #pragma unroll
        for (int k8 = 1; k8 < 8; ++k8) {
            const float* p = st4 + ((size_t)k8 * N_ + n) * 8;
            float4 v  = *reinterpret_cast<const float4*>(p);
            float4 kf = *reinterpret_cast<const float4*>(p + 4);
            float W0 = v.x, W1 = v.y, W2 = v.z, W3 = v.w;
            int   P0 = __float_as_int(kf.x), P1 = __float_as_int(kf.y);
            int   P2 = __float_as_int(kf.z), P3 = __float_as_int(kf.w);
            MERGE2(V0,K0, V1,K1, V2,K2, V3,K3, W0,P0, W1,P1, W2,P2, W3,P3);
        }
        fidx[tid] = K0;
        oidx[n] = (float)K0;
        if (V1 - V0 < QMARGS) {
            int slot = atomicAdd(&fcount, 1);
            flist[slot] = tid;
            fck[slot][0] = K0; fck[slot][1] = K1;
            fck[slot][2] = K2; fck[slot][3] = K3;
        }
    }
    __syncthreads();

    const int fc = fcount;
    for (int i = wave; i < fc; i += 4) {
        const int pl = flist[i];
        const int nn = p0 + pl;
        const int bb = nn >> 10, hw = nn & 1023;
        const float* zb = z + (size_t)bb * (D_ * HW_) + hw;
        float zf[4];
        #pragma unroll
        for (int j = 0; j < 4; ++j) zf[j] = zb[(size_t)(lane * 4 + j) * HW_];

        const float An = A32[nn];
        float bd = 3.4e38f;
        int   bk = 0x7fffffff;
        #pragma unroll
        for (int c = 0; c < 4; ++c) {
            int k = fck[i][c];
            float4 c4 = *reinterpret_cast<const float4*>(cb + (size_t)k * D_ + lane * 4);
            double acc = 0.0;
            acc = fma((double)c4.x, (double)zf[0], acc);
            acc = fma((double)c4.y, (double)zf[1], acc);
            acc = fma((double)c4.z, (double)zf[2], acc);
            acc = fma((double)c4.w, (double)zf[3], acc);
            #pragma unroll
            for (int off = 1; off <= 32; off <<= 1) acc += __shfl_xor(acc, off, 64);
            float C32 = (float)acc;
            float d32 = __fsub_rn(__fadd_rn(An, B32[k]), __fadd_rn(C32, C32));
            if (d32 < bd || (d32 == bd && k < bk)) { bd = d32; bk = k; }
        }
        if (lane == 0) { oidx[nn] = (float)bk; fidx[pl] = bk; }
    }
    __syncthreads();

    if (shadow && p0 >= 16384 && p0 < 24576) return;
    const int s_nl = tid & 63;
    const int s_dw = tid >> 6;
    const int b    = p0 >> 10;
    const int hw0  = p0 & 1023;
    const int idxn = fidx[s_nl];
    const float4* crow = reinterpret_cast<const float4*>(cb + (size_t)idxn * D_);
    float* zqb = zq + (size_t)b * (D_ * HW_) + hw0;
    #pragma unroll
    for (int rr = 0; rr < 16; ++rr) {
        int d4 = s_dw * 16 + rr;
        float4 c4 = crow[d4];
        int d = d4 * 4;
        zqb[(size_t)(d + 0) * HW_ + s_nl] = c4.x;
        zqb[(size_t)(d + 1) * HW_ + s_nl] = c4.y;
        zqb[(size_t)(d + 2) * HW_ + s_nl] = c4.z;
        zqb[(size_t)(d + 3) * HW_ + s_nl] = c4.w;
    }
}

// ---------------------------------------------------------------------------
__global__ __launch_bounds__(256) void gather2_kernel(const float* __restrict__ cb,
                                                      const float* __restrict__ oidx,
                                                      float* __restrict__ zq,
                                                      int base) {
    const int tid  = threadIdx.x;
    const int s_nl = tid & 63;
    const int s_dw = tid >> 6;
    const int p0   = base + blockIdx.x * 64;
    const int b    = p0 >> 10;
    const int hw0  = p0 & 1023;

    int idxn = (int)oidx[p0 + s_nl];
    const float4* crow = reinterpret_cast<const float4*>(cb + (size_t)idxn * D_);
    float* zqb = zq + (size_t)b * (D_ * HW_) + hw0;
    #pragma unroll
    for (int r = 0; r < 16; ++r) {
        int d4 = s_dw * 16 + r;
        float4 c4 = crow[d4];
        int d = d4 * 4;
        zqb[(size_t)(d + 0) * HW_ + s_nl] = c4.x;
        zqb[(size_t)(d + 1) * HW_ + s_nl] = c4.y;
        zqb[(size_t)(d + 2) * HW_ + s_nl] = c4.z;
        zqb[(size_t)(d + 3) * HW_ + s_nl] = c4.w;
    }
}

extern "C" void kernel_launch(void* const* d_in, const int* in_sizes, int n_in,
                              void* d_out, int out_size, void* d_ws, size_t ws_size,
                              hipStream_t stream) {
    const float* z  = (const float*)d_in[0];   // [32,256,32,32] fp32
    const float* cb = (const float*)d_in[1];   // [1024,256] fp32

    float* zq   = (float*)d_out;
    float* oidx = zq + (size_t)N_ * D_;        // byte 33554432

    char* ws = (char*)d_ws;
    float* B32  = (float*)(ws + 0);
    float* hbF  = (float*)(ws + 4096);
    float* A32  = (float*)(ws + 8192);
    half8* cbAf = (half8*)(ws + 139264);       // ends 663552

    char*  zqb = (char*)zq;
    half8* zBf = (half8*)zqb;                  // 16 MB

    // st4: prefer ws (no zq shadow -> single-pass gather); fallback to zq
    const size_t ST4_BYTES = (size_t)8 * N_ * 32;   // 8 MB
    bool ws_big = ws_size >= (size_t)663552 + ST4_BYTES;
    float* st4  = ws_big ? (float*)(ws + 663552)
                         : (float*)(zqb + 16777216);
    int shadow  = ws_big ? 0 : 1;

    prep_kernel<<<2180, 256, 0, stream>>>(z, cb, A32, B32, hbF, cbAf, zBf);
    vq_screen16<<<4096, 256, 0, stream>>>(zBf, cbAf, hbF, st4);
    finish_kernel<<<N_ / 64, 256, 0, stream>>>(st4, A32, B32, cb, z, oidx, zq, shadow);
    if (shadow)
        gather2_kernel<<<128, 256, 0, stream>>>(cb, oidx, zq, 16384);
}